// Round 14
// baseline (782.385 us; speedup 1.0000x reference)
//
#include <hip/hip_runtime.h>

// Decoder layer: x -> rms -> QKV -> causal attn -> +x@wo -> rms -> SwiGLU -> +down
// B=2 S=2048 H=2048 NH=16 HD=128 FF=8192, fp32 I/O, bf16 MFMA compute.
// R14 = R13 + attention q-tile pairing: block handles (qtA=15-g, qtB=g),
// staging K/V once for both (B's range is a subset of A's). Perfect compute
// balance (17 iter/block), ~26% less attn staging, LDS 128->96 KB.

#define HH 2048
#define FF 8192
#define BB 2
#define SS 2048
#define NHH 16
#define HDD 128
#define MM (BB * SS)  // 4096 rows

typedef __attribute__((ext_vector_type(8))) short short8;
typedef __attribute__((ext_vector_type(4))) short short4v;
typedef __attribute__((ext_vector_type(4))) float f32x4;

#define DEV __device__ __forceinline__

DEV short f2bf(float f) {  // RNE f32->bf16
  unsigned u = __builtin_bit_cast(unsigned, f);
  u += 0x7fffu + ((u >> 16) & 1u);
  return (short)(u >> 16);
}
DEV float bf2f(short s) {
  unsigned u = ((unsigned)(unsigned short)s) << 16;
  return __builtin_bit_cast(float, u);
}

// async global->LDS, 16B per lane; lds ptr must be wave-uniform, HW adds lane*16
#define GLL16(gp, lp)                                                    \
  __builtin_amdgcn_global_load_lds(                                      \
      (const __attribute__((address_space(1))) void*)(gp),               \
      (__attribute__((address_space(3))) void*)(lp), 16, 0, 0)

// ---------------- transpose+cast tile body: W[K][N] f32 -> Wt[N][K] bf16 ----
DEV void tc_tile(const float* __restrict__ W, short* __restrict__ Wt,
                 int K, int N, int n0, int k0, int t) {
  __shared__ float tile[32][33];
  int r = t >> 3, c4 = (t & 7) << 2;
  f32x4 v = *(const f32x4*)&W[(long)(k0 + r) * N + n0 + c4];
#pragma unroll
  for (int j = 0; j < 4; ++j) tile[r][c4 + j] = v[j];
  __syncthreads();
  short4v o;
#pragma unroll
  for (int j = 0; j < 4; ++j) o[j] = f2bf(tile[c4 + j][r]);
  *(short4v*)&Wt[(long)(n0 + r) * K + k0 + c4] = o;
}

__global__ __launch_bounds__(256) void transpose_qkvo(
    const float* __restrict__ wq, const float* __restrict__ wk,
    const float* __restrict__ wv, const float* __restrict__ wo,
    short* __restrict__ dst) {
  int bid = blockIdx.x;              // 4 * 64*64 = 16384 blocks
  int seg = bid >> 12, local = bid & 4095;
  const float* W = seg == 0 ? wq : seg == 1 ? wk : seg == 2 ? wv : wo;
  short* Wt = dst + (size_t)seg * HH * HH;
  int n0 = (local & 63) << 5, k0 = (local >> 6) << 5;
  tc_tile(W, Wt, HH, HH, n0, k0, threadIdx.x);
}

__global__ __launch_bounds__(256) void transpose_ffn(
    const float* __restrict__ wgt, const float* __restrict__ wup,
    const float* __restrict__ wdn, short* __restrict__ wtg,
    short* __restrict__ wtd) {
  int bid = blockIdx.x;              // 3 * 16384 = 49152 blocks
  int seg = bid >> 14, local = bid & 16383;
  int t = threadIdx.x;
  if (seg < 2) {
    const float* W = seg == 0 ? wgt : wup;
    short* Wt = wtg + (size_t)seg * HH * FF;
    int n0 = (local & 255) << 5, k0 = (local >> 8) << 5;
    tc_tile(W, Wt, HH, FF, n0, k0, t);
  } else {
    int n0 = (local & 63) << 5, k0 = (local >> 6) << 5;
    tc_tile(wdn, wtd, FF, HH, n0, k0, t);
  }
}

// ---------------- RMSNorm row kernel: f32 in -> bf16 out --------------------
__global__ __launch_bounds__(256) void rmsnorm_k(const float* __restrict__ x,
                                                 const float* __restrict__ g,
                                                 short* __restrict__ out) {
  int row = blockIdx.x;
  int t = threadIdx.x;
  const float* xr = x + (long)row * HH;
  f32x4 v0 = *(const f32x4*)(xr + t * 4);
  f32x4 v1 = *(const f32x4*)(xr + 1024 + t * 4);
  float ss = v0[0] * v0[0] + v0[1] * v0[1] + v0[2] * v0[2] + v0[3] * v0[3] +
             v1[0] * v1[0] + v1[1] * v1[1] + v1[2] * v1[2] + v1[3] * v1[3];
#pragma unroll
  for (int off = 1; off < 64; off <<= 1) ss += __shfl_xor(ss, off);
  __shared__ float red[4];
  if ((t & 63) == 0) red[t >> 6] = ss;
  __syncthreads();
  float tot = red[0] + red[1] + red[2] + red[3];
  float rs = rsqrtf(tot * (1.0f / HH) + 1e-6f);
  f32x4 g0 = *(const f32x4*)(g + t * 4);
  f32x4 g1 = *(const f32x4*)(g + 1024 + t * 4);
  short4v o0, o1;
#pragma unroll
  for (int e = 0; e < 4; ++e) {
    o0[e] = f2bf(v0[e] * rs * g0[e]);
    o1[e] = f2bf(v1[e] * rs * g1[e]);
  }
  *(short4v*)(out + (long)row * HH + t * 4) = o0;
  *(short4v*)(out + (long)row * HH + 1024 + t * 4) = o1;
}

// ---------------- bf16 MFMA GEMM (m97 128x128, 2-phase, BK=64) --------------
// Proven core. MINW=4 caps regs at ~128 total/wave -> 4 waves/SIMD
// (R10: 216->171 us, MfmaUtil 27.5->35.3, no spill).
// EPI: 0 plain bf16 [M][N]; 2 bf16 Vt [b,h,d,s]; 3 f32 out = aux + acc;
//      4 bf16 out = silu(aux bf16)*acc; 5 QKV concat (N=6144).
template <int EPI, int MINW>
__global__ __launch_bounds__(256, MINW) void gemm_bt(
    const short* __restrict__ A, const short* __restrict__ Bt,
    int M, int N, int K, void* out, const void* aux) {
  __shared__ short As[128 * 64];
  __shared__ short Bs[128 * 64];
  int nbn = N >> 7;
  int nwg = gridDim.x;
  int bid = blockIdx.x;
  // bijective XCD swizzle (m204)
  int qq = nwg >> 3, rr = nwg & 7;
  int xcd = bid & 7, lid = bid >> 3;
  int wg = (xcd < rr ? xcd * (qq + 1) : rr * (qq + 1) + (xcd - rr) * qq) + lid;
  // GM=16 grouped supertile (R7: FETCH 453->164 MB)
  const int GM = 16;
  int gsz = GM * nbn;
  int gid = wg / gsz, rem = wg % gsz;
  int bm = gid * GM + (rem % GM);
  int bn = rem / GM;
  int t = threadIdx.x, w = t >> 6, lane = t & 63, lg = lane >> 4, c = lane & 15;
  int wr = w >> 1, wc = w & 1;
  const short* Abase = A + (long)bm * 128 * K;
  const short* Bbase = Bt + (long)bn * 128 * K;
  f32x4 acc[4][4] = {};
  int nk = K >> 6;
  for (int kt = 0; kt < nk; ++kt) {
    int k0 = kt << 6;
    __syncthreads();
#pragma unroll
    for (int i = 0; i < 4; ++i) {
      int idx = i * 256 + t;
      int row = idx >> 3, p = idx & 7;
      int col = k0 + ((p ^ (row & 7)) << 3);
      GLL16(Abase + (long)row * K + col, As + (i * 256 + w * 64) * 8);
      GLL16(Bbase + (long)row * K + col, Bs + (i * 256 + w * 64) * 8);
    }
    __syncthreads();
#pragma unroll
    for (int kk = 0; kk < 2; ++kk) {
      short8 af[4], bfr[4];
#pragma unroll
      for (int m = 0; m < 4; ++m) {
        int row = wr * 64 + m * 16 + c;
        af[m] = *(const short8*)(As + row * 64 + ((((kk << 2) | lg) ^ (row & 7)) << 3));
      }
#pragma unroll
      for (int n = 0; n < 4; ++n) {
        int row = wc * 64 + n * 16 + c;
        bfr[n] = *(const short8*)(Bs + row * 64 + ((((kk << 2) | lg) ^ (row & 7)) << 3));
      }
#pragma unroll
      for (int m = 0; m < 4; ++m)
#pragma unroll
        for (int n = 0; n < 4; ++n)
          acc[m][n] = __builtin_amdgcn_mfma_f32_16x16x32_bf16(af[m], bfr[n], acc[m][n], 0, 0, 0);
    }
  }
#pragma unroll
  for (int m = 0; m < 4; ++m) {
#pragma unroll
    for (int n = 0; n < 4; ++n) {
      int rL = wr * 64 + m * 16 + lg * 4;
      int cL = wc * 64 + n * 16 + c;
      long rg = (long)bm * 128 + rL;
      long cg = (long)bn * 128 + cL;
      if (EPI == 2) {
        int b = (int)(rg >> 11), s = (int)(rg & 2047);
        int head = (int)(cg >> 7), d = (int)(cg & 127);
        short4v pk;
#pragma unroll
        for (int j = 0; j < 4; ++j) pk[j] = f2bf(acc[m][n][j]);
        *(short4v*)((short*)out + ((long)(b * NHH + head) * HDD + d) * SS + s) = pk;
      } else if (EPI == 5) {
        short* base = (short*)out;
        int mat = (int)(cg >> 11);         // 0=q, 1=k, 2=v (uniform per block)
        int cc = (int)(cg & 2047);
        int head = cc >> 7, d = cc & 127;
        if (mat == 2) {                    // vt[b*NH+h][d][s], packed 4 s
          int b = (int)(rg >> 11), s = (int)(rg & 2047);
          short4v pk;
#pragma unroll
          for (int j = 0; j < 4; ++j) pk[j] = f2bf(acc[m][n][j]);
          *(short4v*)(base + (size_t)2 * MM * HH +
                      ((long)(b * NHH + head) * HDD + d) * SS + s) = pk;
        } else {                           // q/k: [b*NH+h][s][d]
          short* dst = base + (size_t)mat * MM * HH;
#pragma unroll
          for (int j = 0; j < 4; ++j) {
            long r = rg + j;
            int b = (int)(r >> 11), s = (int)(r & 2047);
            dst[((long)(b * NHH + head) * SS + s) * HDD + d] = f2bf(acc[m][n][j]);
          }
        }
      } else {
#pragma unroll
        for (int j = 0; j < 4; ++j) {
          long r = rg + j;
          float v = acc[m][n][j];
          if (EPI == 0) {
            ((short*)out)[r * N + cg] = f2bf(v);
          } else if (EPI == 3) {
            ((float*)out)[r * N + cg] = ((const float*)aux)[r * N + cg] + v;
          } else if (EPI == 4) {
            float gv = bf2f(((const short*)aux)[r * N + cg]);
            float sg = gv / (1.0f + __expf(-gv));
            ((short*)out)[r * N + cg] = f2bf(sg * v);
          }
        }
      }
    }
  }
}

// ---------------- causal flash attention (paired q-tiles) -------------------
// 256 blocks; block handles qtA=15-g (long) and qtB=g (short), staging each
// K/V tile ONCE for both (B's kv range subset of A's). Compute perfectly
// balanced: (qtA+1)+(qtB+1) = 17 tile-passes per block. P buffer aliases the
// dead Q staging buffer (Q extracted to registers in prologue); all hazards
// separated by >=1 __syncthreads. P swizzle (row&7)^((row>>3)&7) both sides
// (R11: conflicts 9.5M -> ~0). bh->XCD grouping keeps a head's K/V in one L2.
__global__ __launch_bounds__(512) void attn_k(const short* __restrict__ Qh,
                                              const short* __restrict__ Kh,
                                              const short* __restrict__ Vt,
                                              short* __restrict__ Ob) {
  __shared__ short QPs[128 * 128];  // Q stage -> P tile
  __shared__ short Ks[128 * 128];
  __shared__ short Vs[128 * 128];
  int bid = blockIdx.x;                       // 256 blocks
  int bh = (bid & 7) * 4 + ((bid >> 3) & 3);  // 4 heads per XCD
  int g = bid >> 5;                           // 0..7
  int qtA = 15 - g, qtB = g;
  int t = threadIdx.x, w = t >> 6, lane = t & 63, lg = lane >> 4, c = lane & 15;
  const short* Qb = Qh + (long)bh * SS * HDD;
  const short* Kb = Kh + (long)bh * SS * HDD;
  const short* Vb = Vt + (long)bh * HDD * SS;

  auto stageQ = [&](int q0) {
#pragma unroll
    for (int i = 0; i < 4; ++i) {
      int idx = i * 512 + t;
      int row = idx >> 4, p = idx & 15;
      int col = (p ^ (row & 7)) << 3;
      GLL16(Qb + (long)(q0 + row) * HDD + col, QPs + (i * 512 + w * 64) * 8);
    }
  };
  int qrow = w * 16 + c;
  short8 qfa[4], qfb[4];
  stageQ(qtA << 7);
  __syncthreads();
#pragma unroll
  for (int kk = 0; kk < 4; ++kk)
    qfa[kk] = *(const short8*)(QPs + qrow * 128 + ((((kk << 2) | lg) ^ (qrow & 7)) << 3));
  __syncthreads();  // all qfa reads done before Q_B overwrite
  stageQ(qtB << 7);
  __syncthreads();
#pragma unroll
  for (int kk = 0; kk < 4; ++kk)
    qfb[kk] = *(const short8*)(QPs + qrow * 128 + ((((kk << 2) | lg) ^ (qrow & 7)) << 3));
  short* Ps = QPs;  // Q dead from here; first P write is >=2 barriers away

  f32x4 oA[8] = {}, oB[8] = {};
  float mA[4] = {-1e30f, -1e30f, -1e30f, -1e30f};
  float mB[4] = {-1e30f, -1e30f, -1e30f, -1e30f};
  float lA[4] = {0.f, 0.f, 0.f, 0.f};
  float lB[4] = {0.f, 0.f, 0.f, 0.f};
  const float scale = 0.08838834764831845f;  // 1/sqrt(128)

  // one QK^T -> softmax -> PV pass for one q-tile against the staged K/V tile
  auto tile_pass = [&](const short8(&qf)[4], f32x4(&o)[8], float(&mrun)[4],
                       float(&lrun)[4], int q0t, int diag, int kv0) {
    f32x4 sv[8];
#pragma unroll
    for (int n = 0; n < 8; ++n) {
      f32x4 acc = {};
#pragma unroll
      for (int kk = 0; kk < 4; ++kk) {
        int krow = n * 16 + c;
        short8 kf = *(const short8*)(Ks + krow * 128 + ((((kk << 2) | lg) ^ (krow & 7)) << 3));
        acc = __builtin_amdgcn_mfma_f32_16x16x32_bf16(qf[kk], kf, acc, 0, 0, 0);
      }
      sv[n] = acc;
    }
    int qg = q0t + w * 16 + lg * 4;
    if (diag) {
#pragma unroll
      for (int n = 0; n < 8; ++n) {
        int col = kv0 + n * 16 + c;
#pragma unroll
        for (int j = 0; j < 4; ++j) {
          float xv = sv[n][j] * scale;
          sv[n][j] = (col > qg + j) ? -1e30f : xv;
        }
      }
    } else {
#pragma unroll
      for (int n = 0; n < 8; ++n)
#pragma unroll
        for (int j = 0; j < 4; ++j) sv[n][j] *= scale;
    }
    float alpha[4];
#pragma unroll
    for (int j = 0; j < 4; ++j) {
      float mx = sv[0][j];
#pragma unroll
      for (int n = 1; n < 8; ++n) mx = fmaxf(mx, sv[n][j]);
      mx = fmaxf(mx, __shfl_xor(mx, 1));
      mx = fmaxf(mx, __shfl_xor(mx, 2));
      mx = fmaxf(mx, __shfl_xor(mx, 4));
      mx = fmaxf(mx, __shfl_xor(mx, 8));
      float mnew = fmaxf(mrun[j], mx);
      alpha[j] = __expf(mrun[j] - mnew);
      mrun[j] = mnew;
    }
    float rsum[4] = {0.f, 0.f, 0.f, 0.f};
#pragma unroll
    for (int n = 0; n < 8; ++n)
#pragma unroll
      for (int j = 0; j < 4; ++j) {
        float p = __expf(sv[n][j] - mrun[j]);
        sv[n][j] = p;
        rsum[j] += p;
      }
#pragma unroll
    for (int j = 0; j < 4; ++j) {
      rsum[j] += __shfl_xor(rsum[j], 1);
      rsum[j] += __shfl_xor(rsum[j], 2);
      rsum[j] += __shfl_xor(rsum[j], 4);
      rsum[j] += __shfl_xor(rsum[j], 8);
      lrun[j] = lrun[j] * alpha[j] + rsum[j];
    }
#pragma unroll
    for (int n = 0; n < 8; ++n)
#pragma unroll
      for (int j = 0; j < 4; ++j) o[n][j] *= alpha[j];
    // P -> bf16 -> LDS; swizzle (row&7)^((row>>3)&7) both sides
#pragma unroll
    for (int n = 0; n < 8; ++n)
#pragma unroll
      for (int j = 0; j < 4; ++j) {
        int row = w * 16 + lg * 4 + j;
        int slot = (2 * n + (c >> 3)) ^ (row & 7) ^ ((row >> 3) & 7);
        Ps[row * 128 + slot * 8 + (c & 7)] = f2bf(sv[n][j]);
      }
    __syncthreads();
    short8 pf[4];
    int prow = w * 16 + c;
    int pfx = (prow & 7) ^ ((prow >> 3) & 7);
#pragma unroll
    for (int kk = 0; kk < 4; ++kk)
      pf[kk] = *(const short8*)(Ps + prow * 128 + ((((kk << 2) | lg) ^ pfx) << 3));
#pragma unroll
    for (int n = 0; n < 8; ++n) {
#pragma unroll
      for (int kk = 0; kk < 4; ++kk) {
        int vrow = n * 16 + c;
        short8 vf = *(const short8*)(Vs + vrow * 128 + ((((kk << 2) | lg) ^ (vrow & 7)) << 3));
        o[n] = __builtin_amdgcn_mfma_f32_16x16x32_bf16(pf[kk], vf, o[n], 0, 0, 0);
      }
    }
  };

  for (int kt = 0; kt <= qtA; ++kt) {
    int kv0 = kt << 7;
    __syncthreads();  // prior P/V/K readers done before overwrite
#pragma unroll
    for (int i = 0; i < 4; ++i) {
      int idx = i * 512 + t;
      int row = idx >> 4, p = idx & 15;
      int col = (p ^ (row & 7)) << 3;
      GLL16(Kb + (long)(kv0 + row) * HDD + col, Ks + (i * 512 + w * 64) * 8);
      GLL16(Vb + (long)row * SS + kv0 + col, Vs + (i * 512 + w * 64) * 8);
    }
    __syncthreads();  // staging landed
    tile_pass(qfa, oA, mA, lA, qtA << 7, kt == qtA, kv0);
    if (kt <= qtB) {         // block-uniform branch
      __syncthreads();       // all PV_A reads of Ps done before P_B write
      tile_pass(qfb, oB, mB, lB, qtB << 7, kt == qtB, kv0);
    }
  }

  // finalize both tiles: O /= l, write [b][s][head*128+d] bf16
  int head = bh & (NHH - 1), b = bh >> 4;
  auto writeO = [&](f32x4(&o)[8], float(&lrun)[4], int q0t) {
#pragma unroll
    for (int j = 0; j < 4; ++j) {
      float inv = 1.0f / lrun[j];
      int s = q0t + w * 16 + lg * 4 + j;
#pragma unroll
      for (int n = 0; n < 8; ++n) {
        int hcol = head * 128 + n * 16 + c;
        Ob[((long)(b * SS + s)) * HH + hcol] = f2bf(o[n][j] * inv);
      }
    }
  };
  writeO(oA, lA, qtA << 7);
  writeO(oB, lB, qtB << 7);
}

// ---------------------------------------------------------------------------
extern "C" void kernel_launch(void* const* d_in, const int* in_sizes, int n_in,
                              void* d_out, int out_size, void* d_ws, size_t ws_size,
                              hipStream_t stream) {
  (void)in_sizes; (void)n_in; (void)out_size;
  const float* x     = (const float*)d_in[0];
  const float* wq    = (const float*)d_in[2];
  const float* wk    = (const float*)d_in[3];
  const float* wv    = (const float*)d_in[4];
  const float* wo    = (const float*)d_in[5];
  const float* wgt   = (const float*)d_in[6];
  const float* wup   = (const float*)d_in[7];
  const float* wdn   = (const float*)d_in[8];
  const float* gin   = (const float*)d_in[9];
  const float* gpost = (const float*)d_in[10];
  float* out = (float*)d_out;

  const size_t R0 = 0;
  const size_t R1 = (size_t)32 << 20;
  const size_t R2 = (size_t)48 << 20;
  const size_t R3 = (size_t)112 << 20;
  const size_t NEED = (size_t)176 << 20;
  if (ws_size < NEED) return;

  short* wtq = (short*)((char*)d_ws + R0);  // wtq|wtk|wtv contiguous = QKV concat
  short* wto = wtq + (size_t)3 * HH * HH;
  short* wtd = (short*)((char*)d_ws + R0);  // reuse after wo-GEMM
  short* hb  = (short*)((char*)d_ws + R1);
  short* h2  = hb;
  short* qh  = (short*)((char*)d_ws + R2);  // qh|kh|vt|ab
  short* kh  = qh + (size_t)MM * HH;
  short* vt  = kh + (size_t)MM * HH;
  short* ab  = vt + (size_t)MM * HH;
  short* wtg = (short*)((char*)d_ws + R2);  // wtg|wtu, reuse after attn+wo
  short* gateb = (short*)((char*)d_ws + R3);

  dim3 b256(256, 1, 1);
  transpose_qkvo<<<dim3(16384), b256, 0, stream>>>(wq, wk, wv, wo, wtq);

  rmsnorm_k<<<dim3(MM), b256, 0, stream>>>(x, gin, hb);

  dim3 gQKV((MM / 128) * (3 * HH / 128), 1, 1);  // 1536 WGs
  gemm_bt<5, 4><<<gQKV, b256, 0, stream>>>(hb, wtq, MM, 3 * HH, HH, qh, nullptr);

  attn_k<<<dim3(256), dim3(512, 1, 1), 0, stream>>>(qh, kh, vt, ab);

  dim3 gH((MM / 128) * (HH / 128), 1, 1);  // 512 WGs
  gemm_bt<3, 4><<<gH, b256, 0, stream>>>(ab, wto, MM, HH, HH, out, x);

  transpose_ffn<<<dim3(49152), b256, 0, stream>>>(wgt, wup, wdn, wtg, wtd);

  rmsnorm_k<<<dim3(MM), b256, 0, stream>>>(out, gpost, h2);

  // FF GEMMs at MINW=4 (R10 win)
  dim3 gF((MM / 128) * (FF / 128), 1, 1);  // 2048 WGs
  gemm_bt<0, 4><<<gF, b256, 0, stream>>>(h2, wtg, MM, FF, HH, gateb, nullptr);
  gemm_bt<4, 4><<<gF, b256, 0, stream>>>(h2, wtg + (size_t)HH * FF, MM, FF, HH, gateb, gateb);
  gemm_bt<3, 4><<<gH, b256, 0, stream>>>(gateb, wtd, MM, HH, FF, out, out);
}

// Round 15
// 761.986 us; speedup vs baseline: 1.0268x; 1.0268x over previous
//
#include <hip/hip_runtime.h>

// Decoder layer: x -> rms -> QKV -> causal attn -> +x@wo -> rms -> SwiGLU -> +down
// B=2 S=2048 H=2048 NH=16 HD=128 FF=8192, fp32 I/O, bf16 MFMA compute.
// R15 = R13 (session best, 763 us): R14's paired-q-tile attention reverted
// (serialization at 1 block/CU outweighed the staging savings).

#define HH 2048
#define FF 8192
#define BB 2
#define SS 2048
#define NHH 16
#define HDD 128
#define MM (BB * SS)  // 4096 rows

typedef __attribute__((ext_vector_type(8))) short short8;
typedef __attribute__((ext_vector_type(4))) short short4v;
typedef __attribute__((ext_vector_type(4))) float f32x4;

#define DEV __device__ __forceinline__

DEV short f2bf(float f) {  // RNE f32->bf16
  unsigned u = __builtin_bit_cast(unsigned, f);
  u += 0x7fffu + ((u >> 16) & 1u);
  return (short)(u >> 16);
}
DEV float bf2f(short s) {
  unsigned u = ((unsigned)(unsigned short)s) << 16;
  return __builtin_bit_cast(float, u);
}

// async global->LDS, 16B per lane; lds ptr must be wave-uniform, HW adds lane*16
#define GLL16(gp, lp)                                                    \
  __builtin_amdgcn_global_load_lds(                                      \
      (const __attribute__((address_space(1))) void*)(gp),               \
      (__attribute__((address_space(3))) void*)(lp), 16, 0, 0)

// ---------------- transpose+cast tile body: W[K][N] f32 -> Wt[N][K] bf16 ----
DEV void tc_tile(const float* __restrict__ W, short* __restrict__ Wt,
                 int K, int N, int n0, int k0, int t) {
  __shared__ float tile[32][33];
  int r = t >> 3, c4 = (t & 7) << 2;
  f32x4 v = *(const f32x4*)&W[(long)(k0 + r) * N + n0 + c4];
#pragma unroll
  for (int j = 0; j < 4; ++j) tile[r][c4 + j] = v[j];
  __syncthreads();
  short4v o;
#pragma unroll
  for (int j = 0; j < 4; ++j) o[j] = f2bf(tile[c4 + j][r]);
  *(short4v*)&Wt[(long)(n0 + r) * K + k0 + c4] = o;
}

__global__ __launch_bounds__(256) void transpose_qkvo(
    const float* __restrict__ wq, const float* __restrict__ wk,
    const float* __restrict__ wv, const float* __restrict__ wo,
    short* __restrict__ dst) {
  int bid = blockIdx.x;              // 4 * 64*64 = 16384 blocks
  int seg = bid >> 12, local = bid & 4095;
  const float* W = seg == 0 ? wq : seg == 1 ? wk : seg == 2 ? wv : wo;
  short* Wt = dst + (size_t)seg * HH * HH;
  int n0 = (local & 63) << 5, k0 = (local >> 6) << 5;
  tc_tile(W, Wt, HH, HH, n0, k0, threadIdx.x);
}

__global__ __launch_bounds__(256) void transpose_ffn(
    const float* __restrict__ wgt, const float* __restrict__ wup,
    const float* __restrict__ wdn, short* __restrict__ wtg,
    short* __restrict__ wtd) {
  int bid = blockIdx.x;              // 3 * 16384 = 49152 blocks
  int seg = bid >> 14, local = bid & 16383;
  int t = threadIdx.x;
  if (seg < 2) {
    const float* W = seg == 0 ? wgt : wup;
    short* Wt = wtg + (size_t)seg * HH * FF;
    int n0 = (local & 255) << 5, k0 = (local >> 8) << 5;
    tc_tile(W, Wt, HH, FF, n0, k0, t);
  } else {
    int n0 = (local & 63) << 5, k0 = (local >> 6) << 5;
    tc_tile(wdn, wtd, FF, HH, n0, k0, t);
  }
}

// ---------------- RMSNorm row kernel: f32 in -> bf16 out --------------------
__global__ __launch_bounds__(256) void rmsnorm_k(const float* __restrict__ x,
                                                 const float* __restrict__ g,
                                                 short* __restrict__ out) {
  int row = blockIdx.x;
  int t = threadIdx.x;
  const float* xr = x + (long)row * HH;
  f32x4 v0 = *(const f32x4*)(xr + t * 4);
  f32x4 v1 = *(const f32x4*)(xr + 1024 + t * 4);
  float ss = v0[0] * v0[0] + v0[1] * v0[1] + v0[2] * v0[2] + v0[3] * v0[3] +
             v1[0] * v1[0] + v1[1] * v1[1] + v1[2] * v1[2] + v1[3] * v1[3];
#pragma unroll
  for (int off = 1; off < 64; off <<= 1) ss += __shfl_xor(ss, off);
  __shared__ float red[4];
  if ((t & 63) == 0) red[t >> 6] = ss;
  __syncthreads();
  float tot = red[0] + red[1] + red[2] + red[3];
  float rs = rsqrtf(tot * (1.0f / HH) + 1e-6f);
  f32x4 g0 = *(const f32x4*)(g + t * 4);
  f32x4 g1 = *(const f32x4*)(g + 1024 + t * 4);
  short4v o0, o1;
#pragma unroll
  for (int e = 0; e < 4; ++e) {
    o0[e] = f2bf(v0[e] * rs * g0[e]);
    o1[e] = f2bf(v1[e] * rs * g1[e]);
  }
  *(short4v*)(out + (long)row * HH + t * 4) = o0;
  *(short4v*)(out + (long)row * HH + 1024 + t * 4) = o1;
}

// ---------------- bf16 MFMA GEMM (m97 128x128, 2-phase, BK=64) --------------
// Proven core. MINW=4 caps regs at ~128 total/wave -> 4 waves/SIMD
// (R10: 216->171 us, MfmaUtil 27.5->35.3, no spill).
// EPI: 0 plain bf16 [M][N]; 2 bf16 Vt [b,h,d,s]; 3 f32 out = aux + acc;
//      4 bf16 out = silu(aux bf16)*acc; 5 QKV concat (N=6144).
template <int EPI, int MINW>
__global__ __launch_bounds__(256, MINW) void gemm_bt(
    const short* __restrict__ A, const short* __restrict__ Bt,
    int M, int N, int K, void* out, const void* aux) {
  __shared__ short As[128 * 64];
  __shared__ short Bs[128 * 64];
  int nbn = N >> 7;
  int nwg = gridDim.x;
  int bid = blockIdx.x;
  // bijective XCD swizzle (m204)
  int qq = nwg >> 3, rr = nwg & 7;
  int xcd = bid & 7, lid = bid >> 3;
  int wg = (xcd < rr ? xcd * (qq + 1) : rr * (qq + 1) + (xcd - rr) * qq) + lid;
  // GM=16 grouped supertile (R7: FETCH 453->164 MB)
  const int GM = 16;
  int gsz = GM * nbn;
  int gid = wg / gsz, rem = wg % gsz;
  int bm = gid * GM + (rem % GM);
  int bn = rem / GM;
  int t = threadIdx.x, w = t >> 6, lane = t & 63, lg = lane >> 4, c = lane & 15;
  int wr = w >> 1, wc = w & 1;
  const short* Abase = A + (long)bm * 128 * K;
  const short* Bbase = Bt + (long)bn * 128 * K;
  f32x4 acc[4][4] = {};
  int nk = K >> 6;
  for (int kt = 0; kt < nk; ++kt) {
    int k0 = kt << 6;
    __syncthreads();
#pragma unroll
    for (int i = 0; i < 4; ++i) {
      int idx = i * 256 + t;
      int row = idx >> 3, p = idx & 7;
      int col = k0 + ((p ^ (row & 7)) << 3);
      GLL16(Abase + (long)row * K + col, As + (i * 256 + w * 64) * 8);
      GLL16(Bbase + (long)row * K + col, Bs + (i * 256 + w * 64) * 8);
    }
    __syncthreads();
#pragma unroll
    for (int kk = 0; kk < 2; ++kk) {
      short8 af[4], bfr[4];
#pragma unroll
      for (int m = 0; m < 4; ++m) {
        int row = wr * 64 + m * 16 + c;
        af[m] = *(const short8*)(As + row * 64 + ((((kk << 2) | lg) ^ (row & 7)) << 3));
      }
#pragma unroll
      for (int n = 0; n < 4; ++n) {
        int row = wc * 64 + n * 16 + c;
        bfr[n] = *(const short8*)(Bs + row * 64 + ((((kk << 2) | lg) ^ (row & 7)) << 3));
      }
#pragma unroll
      for (int m = 0; m < 4; ++m)
#pragma unroll
        for (int n = 0; n < 4; ++n)
          acc[m][n] = __builtin_amdgcn_mfma_f32_16x16x32_bf16(af[m], bfr[n], acc[m][n], 0, 0, 0);
    }
  }
#pragma unroll
  for (int m = 0; m < 4; ++m) {
#pragma unroll
    for (int n = 0; n < 4; ++n) {
      int rL = wr * 64 + m * 16 + lg * 4;
      int cL = wc * 64 + n * 16 + c;
      long rg = (long)bm * 128 + rL;
      long cg = (long)bn * 128 + cL;
      if (EPI == 2) {
        int b = (int)(rg >> 11), s = (int)(rg & 2047);
        int head = (int)(cg >> 7), d = (int)(cg & 127);
        short4v pk;
#pragma unroll
        for (int j = 0; j < 4; ++j) pk[j] = f2bf(acc[m][n][j]);
        *(short4v*)((short*)out + ((long)(b * NHH + head) * HDD + d) * SS + s) = pk;
      } else if (EPI == 5) {
        short* base = (short*)out;
        int mat = (int)(cg >> 11);         // 0=q, 1=k, 2=v (uniform per block)
        int cc = (int)(cg & 2047);
        int head = cc >> 7, d = cc & 127;
        if (mat == 2) {                    // vt[b*NH+h][d][s], packed 4 s
          int b = (int)(rg >> 11), s = (int)(rg & 2047);
          short4v pk;
#pragma unroll
          for (int j = 0; j < 4; ++j) pk[j] = f2bf(acc[m][n][j]);
          *(short4v*)(base + (size_t)2 * MM * HH +
                      ((long)(b * NHH + head) * HDD + d) * SS + s) = pk;
        } else {                           // q/k: [b*NH+h][s][d]
          short* dst = base + (size_t)mat * MM * HH;
#pragma unroll
          for (int j = 0; j < 4; ++j) {
            long r = rg + j;
            int b = (int)(r >> 11), s = (int)(r & 2047);
            dst[((long)(b * NHH + head) * SS + s) * HDD + d] = f2bf(acc[m][n][j]);
          }
        }
      } else {
#pragma unroll
        for (int j = 0; j < 4; ++j) {
          long r = rg + j;
          float v = acc[m][n][j];
          if (EPI == 0) {
            ((short*)out)[r * N + cg] = f2bf(v);
          } else if (EPI == 3) {
            ((float*)out)[r * N + cg] = ((const float*)aux)[r * N + cg] + v;
          } else if (EPI == 4) {
            float gv = bf2f(((const short*)aux)[r * N + cg]);
            float sg = gv / (1.0f + __expf(-gv));
            ((short*)out)[r * N + cg] = f2bf(sg * v);
          }
        }
      }
    }
  }
}

// ---------------- causal flash attention (R11/R13 version) ------------------
// Grid: 1D 512 blocks. bh->XCD grouping: all 16 q-tiles of a head land on one
// XCD (4 MB K/V per XCD = L2-fit); longest q-tiles launch first (tail fix).
// P LDS swizzle: f(row) = (row&7) ^ ((row>>3)&7) on BOTH write and read —
// breaks the lg-pair bank duplication of the u16 P-writes (R10: 9.5M
// conflicts). b128 reads stay 2 lanes/slot per quarter-wave = free.
__global__ __launch_bounds__(512) void attn_k(const short* __restrict__ Qh,
                                              const short* __restrict__ Kh,
                                              const short* __restrict__ Vt,
                                              short* __restrict__ Ob) {
  __shared__ short Qs[128 * 128];
  __shared__ short Ks[128 * 128];
  __shared__ short Vs[128 * 128];
  __shared__ short Ps[128 * 128];
  int bid = blockIdx.x;
  int bh = (bid & 7) * 4 + ((bid >> 3) & 3);  // 4 heads per XCD
  int qt = 15 - (bid >> 5);                   // longest first
  int t = threadIdx.x, w = t >> 6, lane = t & 63, lg = lane >> 4, c = lane & 15;
  int q0 = qt << 7;
  const short* Qb = Qh + (long)bh * SS * HDD;
  const short* Kb = Kh + (long)bh * SS * HDD;
  const short* Vb = Vt + (long)bh * HDD * SS;
#pragma unroll
  for (int i = 0; i < 4; ++i) {
    int idx = i * 512 + t;
    int row = idx >> 4, p = idx & 15;
    int col = (p ^ (row & 7)) << 3;
    GLL16(Qb + (long)(q0 + row) * HDD + col, Qs + (i * 512 + w * 64) * 8);
  }
  __syncthreads();
  short8 qf[4];
  int qrow = w * 16 + c;
#pragma unroll
  for (int kk = 0; kk < 4; ++kk)
    qf[kk] = *(const short8*)(Qs + qrow * 128 + ((((kk << 2) | lg) ^ (qrow & 7)) << 3));

  f32x4 o[8] = {};
  float mrun[4] = {-1e30f, -1e30f, -1e30f, -1e30f};
  float lrun[4] = {0.f, 0.f, 0.f, 0.f};
  const float scale = 0.08838834764831845f;
  for (int kt = 0; kt <= qt; ++kt) {
    int kv0 = kt << 7;
    __syncthreads();
#pragma unroll
    for (int i = 0; i < 4; ++i) {
      int idx = i * 512 + t;
      int row = idx >> 4, p = idx & 15;
      int col = (p ^ (row & 7)) << 3;
      GLL16(Kb + (long)(kv0 + row) * HDD + col, Ks + (i * 512 + w * 64) * 8);
      GLL16(Vb + (long)row * SS + kv0 + col, Vs + (i * 512 + w * 64) * 8);
    }
    __syncthreads();
    f32x4 sv[8];
#pragma unroll
    for (int n = 0; n < 8; ++n) {
      f32x4 acc = {};
#pragma unroll
      for (int kk = 0; kk < 4; ++kk) {
        int krow = n * 16 + c;
        short8 kf = *(const short8*)(Ks + krow * 128 + ((((kk << 2) | lg) ^ (krow & 7)) << 3));
        acc = __builtin_amdgcn_mfma_f32_16x16x32_bf16(qf[kk], kf, acc, 0, 0, 0);
      }
      sv[n] = acc;
    }
    int qg = q0 + w * 16 + lg * 4;
    if (kt == qt) {
#pragma unroll
      for (int n = 0; n < 8; ++n) {
        int col = kv0 + n * 16 + c;
#pragma unroll
        for (int j = 0; j < 4; ++j) {
          float xv = sv[n][j] * scale;
          sv[n][j] = (col > qg + j) ? -1e30f : xv;
        }
      }
    } else {
#pragma unroll
      for (int n = 0; n < 8; ++n)
#pragma unroll
        for (int j = 0; j < 4; ++j) sv[n][j] *= scale;
    }
    float alpha[4];
#pragma unroll
    for (int j = 0; j < 4; ++j) {
      float mx = sv[0][j];
#pragma unroll
      for (int n = 1; n < 8; ++n) mx = fmaxf(mx, sv[n][j]);
      mx = fmaxf(mx, __shfl_xor(mx, 1));
      mx = fmaxf(mx, __shfl_xor(mx, 2));
      mx = fmaxf(mx, __shfl_xor(mx, 4));
      mx = fmaxf(mx, __shfl_xor(mx, 8));
      float mnew = fmaxf(mrun[j], mx);
      alpha[j] = __expf(mrun[j] - mnew);
      mrun[j] = mnew;
    }
    float rsum[4] = {0.f, 0.f, 0.f, 0.f};
#pragma unroll
    for (int n = 0; n < 8; ++n)
#pragma unroll
      for (int j = 0; j < 4; ++j) {
        float p = __expf(sv[n][j] - mrun[j]);
        sv[n][j] = p;
        rsum[j] += p;
      }
#pragma unroll
    for (int j = 0; j < 4; ++j) {
      rsum[j] += __shfl_xor(rsum[j], 1);
      rsum[j] += __shfl_xor(rsum[j], 2);
      rsum[j] += __shfl_xor(rsum[j], 4);
      rsum[j] += __shfl_xor(rsum[j], 8);
      lrun[j] = lrun[j] * alpha[j] + rsum[j];
    }
#pragma unroll
    for (int n = 0; n < 8; ++n)
#pragma unroll
      for (int j = 0; j < 4; ++j) o[n][j] *= alpha[j];
    // P -> bf16 -> LDS; swizzle f(row) = (row&7)^((row>>3)&7) kills lg-dup
#pragma unroll
    for (int n = 0; n < 8; ++n)
#pragma unroll
      for (int j = 0; j < 4; ++j) {
        int row = w * 16 + lg * 4 + j;
        int slot = (2 * n + (c >> 3)) ^ (row & 7) ^ ((row >> 3) & 7);
        Ps[row * 128 + slot * 8 + (c & 7)] = f2bf(sv[n][j]);
      }
    __syncthreads();
    short8 pf[4];
    int prow = w * 16 + c;
    int pfx = (prow & 7) ^ ((prow >> 3) & 7);
#pragma unroll
    for (int kk = 0; kk < 4; ++kk)
      pf[kk] = *(const short8*)(Ps + prow * 128 + ((((kk << 2) | lg) ^ pfx) << 3));
#pragma unroll
    for (int n = 0; n < 8; ++n) {
#pragma unroll
      for (int kk = 0; kk < 4; ++kk) {
        int vrow = n * 16 + c;
        short8 vf = *(const short8*)(Vs + vrow * 128 + ((((kk << 2) | lg) ^ (vrow & 7)) << 3));
        o[n] = __builtin_amdgcn_mfma_f32_16x16x32_bf16(pf[kk], vf, o[n], 0, 0, 0);
      }
    }
  }
  int head = bh & (NHH - 1), b = bh >> 4;
#pragma unroll
  for (int j = 0; j < 4; ++j) {
    float inv = 1.0f / lrun[j];
    int s = q0 + w * 16 + lg * 4 + j;
#pragma unroll
    for (int n = 0; n < 8; ++n) {
      int hcol = head * 128 + n * 16 + c;
      Ob[((long)(b * SS + s)) * HH + hcol] = f2bf(o[n][j] * inv);
    }
  }
}

// ---------------------------------------------------------------------------
extern "C" void kernel_launch(void* const* d_in, const int* in_sizes, int n_in,
                              void* d_out, int out_size, void* d_ws, size_t ws_size,
                              hipStream_t stream) {
  (void)in_sizes; (void)n_in; (void)out_size;
  const float* x     = (const float*)d_in[0];
  const float* wq    = (const float*)d_in[2];
  const float* wk    = (const float*)d_in[3];
  const float* wv    = (const float*)d_in[4];
  const float* wo    = (const float*)d_in[5];
  const float* wgt   = (const float*)d_in[6];
  const float* wup   = (const float*)d_in[7];
  const float* wdn   = (const float*)d_in[8];
  const float* gin   = (const float*)d_in[9];
  const float* gpost = (const float*)d_in[10];
  float* out = (float*)d_out;

  const size_t R0 = 0;
  const size_t R1 = (size_t)32 << 20;
  const size_t R2 = (size_t)48 << 20;
  const size_t R3 = (size_t)112 << 20;
  const size_t NEED = (size_t)176 << 20;
  if (ws_size < NEED) return;

  short* wtq = (short*)((char*)d_ws + R0);  // wtq|wtk|wtv contiguous = QKV concat
  short* wto = wtq + (size_t)3 * HH * HH;
  short* wtd = (short*)((char*)d_ws + R0);  // reuse after wo-GEMM
  short* hb  = (short*)((char*)d_ws + R1);
  short* h2  = hb;
  short* qh  = (short*)((char*)d_ws + R2);  // qh|kh|vt|ab
  short* kh  = qh + (size_t)MM * HH;
  short* vt  = kh + (size_t)MM * HH;
  short* ab  = vt + (size_t)MM * HH;
  short* wtg = (short*)((char*)d_ws + R2);  // wtg|wtu, reuse after attn+wo
  short* gateb = (short*)((char*)d_ws + R3);

  dim3 b256(256, 1, 1);
  transpose_qkvo<<<dim3(16384), b256, 0, stream>>>(wq, wk, wv, wo, wtq);

  rmsnorm_k<<<dim3(MM), b256, 0, stream>>>(x, gin, hb);

  dim3 gQKV((MM / 128) * (3 * HH / 128), 1, 1);  // 1536 WGs
  gemm_bt<5, 4><<<gQKV, b256, 0, stream>>>(hb, wtq, MM, 3 * HH, HH, qh, nullptr);

  attn_k<<<dim3(512), dim3(512, 1, 1), 0, stream>>>(qh, kh, vt, ab);

  dim3 gH((MM / 128) * (HH / 128), 1, 1);  // 512 WGs
  gemm_bt<3, 4><<<gH, b256, 0, stream>>>(ab, wto, MM, HH, HH, out, x);

  transpose_ffn<<<dim3(49152), b256, 0, stream>>>(wgt, wup, wdn, wtg, wtd);

  rmsnorm_k<<<dim3(MM), b256, 0, stream>>>(out, gpost, h2);

  // FF GEMMs at MINW=4 (R10 win)
  dim3 gF((MM / 128) * (FF / 128), 1, 1);  // 2048 WGs
  gemm_bt<0, 4><<<gF, b256, 0, stream>>>(h2, wtg, MM, FF, HH, gateb, nullptr);
  gemm_bt<4, 4><<<gF, b256, 0, stream>>>(h2, wtg + (size_t)HH * FF, MM, FF, HH, gateb, gateb);
  gemm_bt<3, 4><<<gH, b256, 0, stream>>>(gateb, wtd, MM, HH, FF, out, out);
}